// Round 5
// baseline (1357.384 us; speedup 1.0000x reference)
//
#include <hip/hip_runtime.h>
#include <math.h>

typedef unsigned short u16;
typedef unsigned int u32;

#define NB 16
#define NC 512
#define NL 4096
#define ND 384
#define NW 256      // pooled length n
#define NIN 512     // inner
#define NFF 1536
#define NM (NB*NW)  // 4096 rows
#define ATT_SCALE 0.125f

__device__ __forceinline__ float gelu_f(float x) {
  return 0.5f * x * (1.f + erff(x * 0.70710678118654752f));
}

// ---- pool: x[b][c][0:4096] (f32) -> mean over windows of 16 -> xpT[(b*256+n)][c]
__global__ __launch_bounds__(256) void pool_kernel(const float* __restrict__ x, float* __restrict__ xpT) {
  int blk = blockIdx.x;            // b*512 + c
  int b = blk >> 9, c = blk & 511;
  int t = threadIdx.x;             // window index n
  const float4* p = (const float4*)(x + (size_t)blk * NL) + t * 4;
  float s = 0.f;
#pragma unroll
  for (int i = 0; i < 4; ++i) {
    float4 v = p[i];
    s += v.x + v.y + v.z + v.w;
  }
  xpT[((size_t)b * NW + t) * NC + c] = s * (1.f / 16.f);
}

// ---- generic f32 transpose: dst[c*R + r] = src[r*C + c]
__global__ void transpose_f(const float* __restrict__ src, float* __restrict__ dst, int R, int C) {
  int idx = blockIdx.x * 256 + threadIdx.x;
  if (idx >= R * C) return;
  int r = idx % R, c = idx / R;
  dst[idx] = src[(size_t)r * C + c];
}

// ---- conv weight reshape: Wcv[(j*384+dp)*384 + d] = local_w[d][dp][j]
__global__ void convw_kernel(const float* __restrict__ lw, float* __restrict__ Wcv) {
  int idx = blockIdx.x * 256 + threadIdx.x;
  if (idx >= 1152 * 384) return;
  int d = idx % 384;
  int r = idx / 384;        // 0..1151
  int j = r / 384;
  int dp = r - j * 384;
  Wcv[idx] = lw[(size_t)d * 1152 + dp * 3 + j];
}

// ---- tiled f32 GEMM. C[m][n] = f(A@B + bias) (+ res)
// BM=128 BN=64 BK=16, 256 threads, 8x4 per-thread microtile.
template<bool GELU>
__global__ __launch_bounds__(256) void gemm_kernel(
    const float* __restrict__ A, const float* __restrict__ Bw,
    const float* __restrict__ bias, const float* __restrict__ res,
    float* __restrict__ C, int M, int N, int K)
{
  __shared__ float As[16][132];  // [k][m], padded: store conflicts 2-way (free)
  __shared__ float Bs[16][64];   // [k][n]
  const int t = threadIdx.x;
  const int bm = blockIdx.y * 128;
  const int bn = blockIdx.x * 64;
  const int tr = t >> 4;         // 0..15 -> rows tr*8..+8
  const int tc = t & 15;         // cols tc*4..+4
  const int la_m = t >> 2;       // 0..63
  const int la_k = (t & 3) * 4;
  const int lb_k = t >> 4;       // 0..15
  const int lb_n = (t & 15) * 4;
  float acc[8][4];
#pragma unroll
  for (int r = 0; r < 8; ++r)
#pragma unroll
    for (int c = 0; c < 4; ++c) acc[r][c] = 0.f;

  for (int k0 = 0; k0 < K; k0 += 16) {
    float4 a0 = *(const float4*)(A + (size_t)(bm + la_m) * K + k0 + la_k);
    float4 a1 = *(const float4*)(A + (size_t)(bm + la_m + 64) * K + k0 + la_k);
    float4 bv = *(const float4*)(Bw + (size_t)(k0 + lb_k) * N + bn + lb_n);
    __syncthreads();
    As[la_k + 0][la_m] = a0.x; As[la_k + 1][la_m] = a0.y;
    As[la_k + 2][la_m] = a0.z; As[la_k + 3][la_m] = a0.w;
    As[la_k + 0][la_m + 64] = a1.x; As[la_k + 1][la_m + 64] = a1.y;
    As[la_k + 2][la_m + 64] = a1.z; As[la_k + 3][la_m + 64] = a1.w;
    *(float4*)&Bs[lb_k][lb_n] = bv;
    __syncthreads();
#pragma unroll
    for (int kk = 0; kk < 16; ++kk) {
      float4 av0 = *(const float4*)&As[kk][tr * 8];
      float4 av1 = *(const float4*)&As[kk][tr * 8 + 4];
      float4 bvv = *(const float4*)&Bs[kk][tc * 4];
      float ar[8] = {av0.x, av0.y, av0.z, av0.w, av1.x, av1.y, av1.z, av1.w};
      float br[4] = {bvv.x, bvv.y, bvv.z, bvv.w};
#pragma unroll
      for (int r = 0; r < 8; ++r)
#pragma unroll
        for (int c = 0; c < 4; ++c) acc[r][c] += ar[r] * br[c];
    }
  }

  const int n = bn + tc * 4;
  float b4[4] = {0.f, 0.f, 0.f, 0.f};
  if (bias) {
    const float4 bb = *(const float4*)(bias + n);
    b4[0] = bb.x; b4[1] = bb.y; b4[2] = bb.z; b4[3] = bb.w;
  }
#pragma unroll
  for (int r = 0; r < 8; ++r) {
    int m = bm + tr * 8 + r;
    float v0 = acc[r][0] + b4[0], v1 = acc[r][1] + b4[1];
    float v2 = acc[r][2] + b4[2], v3 = acc[r][3] + b4[3];
    if (GELU) { v0 = gelu_f(v0); v1 = gelu_f(v1); v2 = gelu_f(v2); v3 = gelu_f(v3); }
    if (res) {
      const float4 rv = *(const float4*)(res + (size_t)m * N + n);
      v0 += rv.x; v1 += rv.y; v2 += rv.z; v3 += rv.w;
    }
    float4 o; o.x = v0; o.y = v1; o.z = v2; o.w = v3;
    *(float4*)(C + (size_t)m * N + n) = o;
  }
}

// ---- layernorm over D=384, f32 in/out/params
__global__ __launch_bounds__(128) void ln_kernel(const float* __restrict__ in,
                                                 const float* __restrict__ g,
                                                 const float* __restrict__ bb,
                                                 float* __restrict__ out)
{
  int row = blockIdx.x, t = threadIdx.x;
  const float* p = in + (size_t)row * ND;
  float v0 = p[t], v1 = p[t + 128], v2 = p[t + 256];
  float s1 = v0 + v1 + v2;
  float s2 = v0 * v0 + v1 * v1 + v2 * v2;
#pragma unroll
  for (int off = 32; off > 0; off >>= 1) {
    s1 += __shfl_down(s1, off);
    s2 += __shfl_down(s2, off);
  }
  __shared__ float sh[4];
  if ((t & 63) == 0) { sh[(t >> 6) * 2] = s1; sh[(t >> 6) * 2 + 1] = s2; }
  __syncthreads();
  float t1 = sh[0] + sh[2], t2 = sh[1] + sh[3];
  float mean = t1 * (1.f / ND);
  float var = t2 * (1.f / ND) - mean * mean;
  float rs = rsqrtf(var + 1e-5f);
  float* q = out + (size_t)row * ND;
  q[t]       = (v0 - mean) * rs * g[t]       + bb[t];
  q[t + 128] = (v1 - mean) * rs * g[t + 128] + bb[t + 128];
  q[t + 256] = (v2 - mean) * rs * g[t + 256] + bb[t + 256];
}

// ---- per-head [n x 64] = f(in[n][0:64]) @ mat[64][64]   (mat f32)
// MODE: 0 plain, 1 relu*SCALE, 2 relu.
template<int MODE>
__global__ __launch_bounds__(256) void nm_kernel(
    const float* __restrict__ in, const float* __restrict__ mat,
    float* __restrict__ out,
    long sb_in, long sh_in, long sn_in,
    long sb_out, long sh_out, long sn_out,
    long mat_sbh)
{
  int bh = blockIdx.x;   // 0..127
  int nq = blockIdx.y;   // 0..3 (64-row slab)
  int b = bh >> 3, h = bh & 7;
  int t = threadIdx.x;
  __shared__ float ms[4096];      // mat [contract][out]
  __shared__ float xs[16][68];    // staged input rows (padded)
  const float* mp = mat + (size_t)bh * mat_sbh;
#pragma unroll
  for (int i = 0; i < 4; ++i) {
    int idx = t + 256 * i;
    ((float4*)ms)[idx] = ((const float4*)mp)[idx];
  }
  const float* ip = in + (size_t)b * sb_in + (size_t)h * sh_in;
  float* op = out + (size_t)b * sb_out + (size_t)h * sh_out;
  int nr = t >> 4, q4 = (t & 15) * 4;
  for (int p = 0; p < 4; ++p) {
    int nbase = nq * 64 + p * 16 + nr;
    __syncthreads();   // mat staged (p==0) / previous pass's readers done
    float4 v = *(const float4*)(ip + (size_t)nbase * sn_in + q4);
    if (MODE == 1) {
      v.x = fmaxf(v.x, 0.f) * ATT_SCALE; v.y = fmaxf(v.y, 0.f) * ATT_SCALE;
      v.z = fmaxf(v.z, 0.f) * ATT_SCALE; v.w = fmaxf(v.w, 0.f) * ATT_SCALE;
    } else if (MODE == 2) {
      v.x = fmaxf(v.x, 0.f); v.y = fmaxf(v.y, 0.f);
      v.z = fmaxf(v.z, 0.f); v.w = fmaxf(v.w, 0.f);
    }
    *(float4*)&xs[nr][q4] = v;
    __syncthreads();
    float fx = 0.f, fy = 0.f, fz = 0.f, fw = 0.f;
#pragma unroll
    for (int d = 0; d < 64; ++d) {
      float a = xs[nr][d];
      const float4 mm = *(const float4*)&ms[d * 64 + q4];
      fx += a * mm.x; fy += a * mm.y; fz += a * mm.z; fw += a * mm.w;
    }
    float4 o; o.x = fx; o.y = fy; o.z = fz; o.w = fw;
    *(float4*)(op + (size_t)nbase * sn_out + q4) = o;
  }
}

// ---- kv[bh][m][d] = sum_n kp[bh][n][m] * v[b][n][h*64+d]
__global__ __launch_bounds__(256) void kv_kernel(const float* __restrict__ qkv,
                                                 const float* __restrict__ kp,
                                                 float* __restrict__ kvb)
{
  int bh = blockIdx.x;
  int b = bh >> 3, h = bh & 7;
  int t = threadIdx.x;
  __shared__ float ks[16][68];
  __shared__ float vs[16][68];
  int m = t >> 2, dq = t & 3;
  int nr = t >> 4, c4 = (t & 15) * 4;
  const float* vbase = qkv + (size_t)b * NW * 1536 + 1024 + h * 64;
  const float* kbase = kp + (size_t)bh * 16384;
  float4 a0 = {0,0,0,0}, a1 = {0,0,0,0}, a2 = {0,0,0,0}, a3 = {0,0,0,0};
  for (int p = 0; p < 16; ++p) {
    __syncthreads();
    *(float4*)&ks[nr][c4] = *(const float4*)(kbase + (size_t)(p * 16 + nr) * 64 + c4);
    *(float4*)&vs[nr][c4] = *(const float4*)(vbase + (size_t)(p * 16 + nr) * 1536 + c4);
    __syncthreads();
#pragma unroll
    for (int nn = 0; nn < 16; ++nn) {
      float a = ks[nn][m];
      const float4 v0 = *(const float4*)&vs[nn][dq * 16 + 0];
      const float4 v1 = *(const float4*)&vs[nn][dq * 16 + 4];
      const float4 v2 = *(const float4*)&vs[nn][dq * 16 + 8];
      const float4 v3 = *(const float4*)&vs[nn][dq * 16 + 12];
      a0.x += a * v0.x; a0.y += a * v0.y; a0.z += a * v0.z; a0.w += a * v0.w;
      a1.x += a * v1.x; a1.y += a * v1.y; a1.z += a * v1.z; a1.w += a * v1.w;
      a2.x += a * v2.x; a2.y += a * v2.y; a2.z += a * v2.z; a2.w += a * v2.w;
      a3.x += a * v3.x; a3.y += a * v3.y; a3.z += a * v3.z; a3.w += a * v3.w;
    }
  }
  float* op = kvb + (size_t)bh * 4096 + (size_t)m * 64 + dq * 16;
  *(float4*)(op + 0) = a0; *(float4*)(op + 4) = a1;
  *(float4*)(op + 8) = a2; *(float4*)(op + 12) = a3;
}

// ---- im2col for conv1d k=3 pad=1 along n (within each batch of 256 rows)
__global__ __launch_bounds__(256) void gather_kernel(const float* __restrict__ h, float* __restrict__ Acv)
{
  int idx = blockIdx.x * 256 + threadIdx.x;   // float4 index over [4096][1152]
  if (idx >= 4096 * 288) return;
  int c4 = idx % 288;
  int m = idx / 288;
  int col = c4 * 4;
  int j = col / 384;
  int d = col - j * 384;
  int n = m & 255;
  int nn = n + j - 1;
  float4 v = {0, 0, 0, 0};
  if (nn >= 0 && nn < 256) v = *(const float4*)(h + (size_t)(m + j - 1) * ND + d);
  ((float4*)Acv)[idx] = v;
}

// ---- final: out[b][c][l] = lerp(hp[b][i0][c], hp[b][i1][c]) + x[b][c][l]  (f32 out)
__global__ __launch_bounds__(256) void final_kernel(const float* __restrict__ hp,
                                                    const float* __restrict__ x,
                                                    float* __restrict__ out)
{
  size_t idx = (size_t)blockIdx.x * 256 + threadIdx.x;   // float4 index, 4 elements each
  int l4 = (int)(idx & 1023);
  int c  = (int)((idx >> 10) & 511);
  int b  = (int)(idx >> 19);
  const float4 xv = ((const float4*)x)[idx];
  float xr[4] = {xv.x, xv.y, xv.z, xv.w};
  float ov[4];
  const float* hpb = hp + (size_t)b * NW * NIN + c;
#pragma unroll
  for (int j = 0; j < 4; ++j) {
    int l = l4 * 4 + j;
    float src = fmaxf((l + 0.5f) * (1.f / 16.f) - 0.5f, 0.f);
    int i0 = (int)src; if (i0 > 255) i0 = 255;
    int i1 = i0 + 1; if (i1 > 255) i1 = 255;
    float w = src - (float)i0;
    float a = hpb[(size_t)i0 * NIN];
    float b2 = hpb[(size_t)i1 * NIN];
    ov[j] = a + (b2 - a) * w + xr[j];
  }
  float4 res; res.x = ov[0]; res.y = ov[1]; res.z = ov[2]; res.w = ov[3];
  ((float4*)out)[idx] = res;
}

extern "C" void kernel_launch(void* const* d_in, const int* in_sizes, int n_in,
                              void* d_out, int out_size, void* d_ws, size_t ws_size,
                              hipStream_t stream)
{
  const float* x          = (const float*)d_in[0];
  const float* proj_in_w  = (const float*)d_in[1];
  const float* proj_in_b  = (const float*)d_in[2];
  const float* norm_in_g  = (const float*)d_in[3];
  const float* norm_in_b  = (const float*)d_in[4];
  const float* ln1_g      = (const float*)d_in[5];
  const float* ln1_b      = (const float*)d_in[6];
  const float* wqkv       = (const float*)d_in[7];
  const float* rf         = (const float*)d_in[8];
  const float* wout       = (const float*)d_in[9];
  const float* bout       = (const float*)d_in[10];
  const float* ln2_g      = (const float*)d_in[11];
  const float* ln2_b      = (const float*)d_in[12];
  const float* ffw1       = (const float*)d_in[13];
  const float* ffb1       = (const float*)d_in[14];
  const float* ffw2       = (const float*)d_in[15];
  const float* ffb2       = (const float*)d_in[16];
  const float* local_w    = (const float*)d_in[17];
  const float* local_b    = (const float*)d_in[18];
  const float* norm_out_g = (const float*)d_in[19];
  const float* norm_out_b = (const float*)d_in[20];
  const float* proj_out_w = (const float*)d_in[21];
  const float* proj_out_b = (const float*)d_in[22];
  float* out = (float*)d_out;

  // ---- Phase-overlaid workspace: 12,582,912 floats = 48 MiB total ----
  float* A = (float*)d_ws;
  float* Br = A + 1572864;
  float* Cr = Br + 6291456;

  float* hbuf = A;
  float* qkvb = Br;                 // [4096][1536]
  float* obuf = Br;                 // [4096][512]   (after kv consumed qkv)
  float* Wcv    = Br;               // [1152][384]   (after FF2 of layer 1)
  float* WT_out = Br + 442368;      // [384][512]
  float* hp     = Br + 638976;      // [4096][512]

  float* xpT   = Cr;                // [4096][512]   (setup)
  float* WT_in = Cr + 2097152;      // [512][384]    (setup)
  float* ypre  = Cr + 2293760;      // [4096][384]   (setup: proj_in out)
  float* ybuf  = Cr;                // [4096][384]   (LN outputs, per phase)
  float* qpb   = Cr;                // [128][256][64]
  float* kpb   = Cr + 2097152;      // [128][256][64]
  float* kvb   = Cr + 4194304;      // [128][64][64]
  float* Acv   = Cr;                // [4096][1152]

  // ---- setup: pool + proj_in + LN_in (all in region C; B untouched)
  pool_kernel<<<8192, 256, 0, stream>>>(x, xpT);
  transpose_f<<<768, 256, 0, stream>>>(proj_in_w, WT_in, 384, 512);
  gemm_kernel<false><<<dim3(6, 32), 256, 0, stream>>>(xpT, WT_in, proj_in_b, nullptr, ypre, NM, 384, 512);
  ln_kernel<<<4096, 128, 0, stream>>>(ypre, norm_in_g, norm_in_b, hbuf);

  const long sbQ = 256L * 1536, shQ = 64, snQ = 1536;   // qkv strides
  const long sbP = 131072, shP = 16384, snP = 64;       // qp/kp strides
  const long sbO = 131072, shO = 64, snO = 512;         // merged-head o strides

  for (int i = 0; i < 2; ++i) {
    ln_kernel<<<4096, 128, 0, stream>>>(hbuf, ln1_g + i * 384, ln1_b + i * 384, ybuf);
    gemm_kernel<false><<<dim3(24, 32), 256, 0, stream>>>(ybuf, wqkv + (size_t)i * 384 * 1536,
                                                         nullptr, nullptr, qkvb, NM, 1536, 384);
    // qp = relu(q)*scale @ rf ; kp = relu(k) @ rf   (overwrites ybuf region — dead)
    nm_kernel<1><<<dim3(128, 4), 256, 0, stream>>>(qkvb, rf + (size_t)i * 4096, qpb,
        sbQ, shQ, snQ, sbP, shP, snP, 0L);
    nm_kernel<2><<<dim3(128, 4), 256, 0, stream>>>(qkvb + 512, rf + (size_t)i * 4096, kpb,
        sbQ, shQ, snQ, sbP, shP, snP, 0L);
    // kv = kp^T @ v  (reassociated attention) — last consumer of qkvb
    kv_kernel<<<128, 256, 0, stream>>>(qkvb, kpb, kvb);
    // o = qp @ kv -> merged heads [4096][512] into B (qkvb dead)
    nm_kernel<0><<<dim3(128, 4), 256, 0, stream>>>(qpb, kvb, obuf,
        sbP, shP, snP, sbO, shO, snO, 4096L);
    // h += o @ wout + bout
    gemm_kernel<false><<<dim3(6, 32), 256, 0, stream>>>(obuf, wout + (size_t)i * 512 * 384,
        bout + i * 384, hbuf, hbuf, NM, 384, 512);
    // FF
    ln_kernel<<<4096, 128, 0, stream>>>(hbuf, ln2_g + i * 384, ln2_b + i * 384, ybuf);
    gemm_kernel<true><<<dim3(24, 32), 256, 0, stream>>>(ybuf, ffw1 + (size_t)i * 384 * 1536,
        ffb1 + i * 1536, nullptr, qkvb, NM, 1536, 384);
    gemm_kernel<false><<<dim3(6, 32), 256, 0, stream>>>(qkvb, ffw2 + (size_t)i * 1536 * 384,
        ffb2 + i * 384, hbuf, hbuf, NM, 384, 1536);
  }

  // ---- local conv (im2col in C, weights in B head, residual)
  convw_kernel<<<1728, 256, 0, stream>>>(local_w, Wcv);
  gather_kernel<<<4608, 256, 0, stream>>>(hbuf, Acv);
  gemm_kernel<false><<<dim3(6, 32), 256, 0, stream>>>(Acv, Wcv, local_b, hbuf, hbuf, NM, 384, 1152);

  // ---- LN_out + proj_out folded before interpolation (interp commutes with linear map)
  ln_kernel<<<4096, 128, 0, stream>>>(hbuf, norm_out_g, norm_out_b, ybuf);
  transpose_f<<<768, 256, 0, stream>>>(proj_out_w, WT_out, 512, 384);
  gemm_kernel<false><<<dim3(8, 32), 256, 0, stream>>>(ybuf, WT_out, proj_out_b, nullptr, hp, NM, 512, 384);

  // ---- interp + residual + f32 store
  final_kernel<<<32768, 256, 0, stream>>>(hp, x, out);
}